// Round 1
// baseline (202.269 us; speedup 1.0000x reference)
//
#include <hip/hip_runtime.h>
#include <math.h>

#define H 8
#define C 32

__device__ __forceinline__ float wave_reduce_max(float v) {
#pragma unroll
    for (int off = 32; off; off >>= 1) v = fmaxf(v, __shfl_xor(v, off, 64));
    return v;
}
__device__ __forceinline__ float wave_reduce_sum(float v) {
#pragma unroll
    for (int off = 32; off; off >>= 1) v += __shfl_xor(v, off, 64);
    return v;
}

// One block (256 threads) per head: compute softmax stats and (optionally) the
// full weight table w[h][m] = exp(att[h][m] - max) / sum.
__global__ __launch_bounds__(256) void softmax_kernel(
        const float* __restrict__ att, float* __restrict__ stats,
        float* __restrict__ wtab, int M, int write_table) {
    __shared__ float sm[4];
    const int h = blockIdx.x;
    const float* __restrict__ row = att + (size_t)h * M;

    // pass 1: max
    float mx = -INFINITY;
    for (int i = threadIdx.x; i < M; i += 256) mx = fmaxf(mx, row[i]);
    mx = wave_reduce_max(mx);
    if ((threadIdx.x & 63) == 0) sm[threadIdx.x >> 6] = mx;
    __syncthreads();
    mx = fmaxf(fmaxf(sm[0], sm[1]), fmaxf(sm[2], sm[3]));
    __syncthreads();

    // pass 2: sum of exp
    float s = 0.f;
    for (int i = threadIdx.x; i < M; i += 256) s += __expf(row[i] - mx);
    s = wave_reduce_sum(s);
    if ((threadIdx.x & 63) == 0) sm[threadIdx.x >> 6] = s;
    __syncthreads();
    s = sm[0] + sm[1] + sm[2] + sm[3];
    const float inv = 1.0f / s;

    if (threadIdx.x == 0) { stats[h] = mx; stats[H + h] = inv; }

    if (write_table) {
        for (int i = threadIdx.x; i < M; i += 256)
            wtab[(size_t)h * M + i] = __expf(row[i] - mx) * inv;
    }
}

// Pooling: each 64-thread block owns a contiguous chunk of nodes.
// lane -> (head h = lane>>3, channel group c = (lane&7)*4). Each lane keeps a
// float4 accumulator; since batch is sorted, the segment id changes rarely and
// the flush (4 atomicAdds per lane) is a uniform, rare event.
template <bool TABLE>
__global__ __launch_bounds__(64) void pool_kernel(
        const float* __restrict__ x, const int* __restrict__ batch,
        const float* __restrict__ att, const float* __restrict__ stats,
        const float* __restrict__ wtab, float* __restrict__ out,
        int M, int Ntot, int chunk) {
    const int start = blockIdx.x * chunk;
    if (start >= Ntot) return;
    const int end = min(start + chunk, Ntot);

    const int lane = threadIdx.x;
    const int h = lane >> 3;
    const int c = (lane & 7) << 2;

    const float* __restrict__ wrow =
        TABLE ? (wtab + (size_t)h * M) : (att + (size_t)h * M);
    const float mh = TABLE ? 0.f : stats[h];
    const float ih = TABLE ? 0.f : stats[H + h];

    int m = start % M;
    int curb = batch[start];
    float ax = 0.f, ay = 0.f, az = 0.f, aw = 0.f;

    for (int n = start; n < end; ++n) {
        const int b = batch[n];  // wave-uniform (n is uniform)
        if (b != curb) {
            float* o = out + (size_t)curb * (H * C) + h * C + c;
            atomicAdd(o + 0, ax); atomicAdd(o + 1, ay);
            atomicAdd(o + 2, az); atomicAdd(o + 3, aw);
            ax = ay = az = aw = 0.f;
            curb = b;
        }
        const float4 xv = *reinterpret_cast<const float4*>(x + (size_t)n * C + c);
        float wv = wrow[m];
        if (!TABLE) wv = __expf(wv - mh) * ih;
        ax = fmaf(xv.x, wv, ax);
        ay = fmaf(xv.y, wv, ay);
        az = fmaf(xv.z, wv, az);
        aw = fmaf(xv.w, wv, aw);
        m = (m + 1 == M) ? 0 : m + 1;
    }
    float* o = out + (size_t)curb * (H * C) + h * C + c;
    atomicAdd(o + 0, ax); atomicAdd(o + 1, ay);
    atomicAdd(o + 2, az); atomicAdd(o + 3, aw);
}

extern "C" void kernel_launch(void* const* d_in, const int* in_sizes, int n_in,
                              void* d_out, int out_size, void* d_ws, size_t ws_size,
                              hipStream_t stream) {
    const float* x     = (const float*)d_in[0];
    const int*   batch = (const int*)d_in[1];
    const float* att   = (const float*)d_in[2];
    float*       out   = (float*)d_out;

    const int Ntot = in_sizes[0] / C;   // total nodes
    const int M    = in_sizes[2] / H;   // nodes per graph slot axis

    float* stats = (float*)d_ws;                       // [2*H] floats
    float* wtab  = (float*)((char*)d_ws + 256);        // [H*M] floats
    const size_t need = 256 + (size_t)H * M * sizeof(float);
    const bool table = (ws_size >= need);

    hipMemsetAsync(d_out, 0, (size_t)out_size * sizeof(float), stream);
    softmax_kernel<<<H, 256, 0, stream>>>(att, stats, table ? wtab : (float*)d_ws,
                                          M, table ? 1 : 0);

    const int chunk = 512;
    const int grid = (Ntot + chunk - 1) / chunk;
    if (table) {
        pool_kernel<true><<<grid, 64, 0, stream>>>(x, batch, att, stats, wtab,
                                                   out, M, Ntot, chunk);
    } else {
        pool_kernel<false><<<grid, 64, 0, stream>>>(x, batch, att, stats, wtab,
                                                    out, M, Ntot, chunk);
    }
}

// Round 2
// 56.596 us; speedup vs baseline: 3.5739x; 3.5739x over previous
//
#include <hip/hip_runtime.h>
#include <math.h>

#define H 8
#define C 32
#define HC 256

__device__ __forceinline__ float wred_max(float v) {
#pragma unroll
    for (int o = 32; o; o >>= 1) v = fmaxf(v, __shfl_xor(v, o, 64));
    return v;
}
__device__ __forceinline__ float wred_sum(float v) {
#pragma unroll
    for (int o = 32; o; o >>= 1) v += __shfl_xor(v, o, 64);
    return v;
}
__device__ __forceinline__ float4 red4_no(float4 v) {
#pragma unroll
    for (int o = 8; o < 64; o <<= 1) {
        v.x += __shfl_xor(v.x, o, 64);
        v.y += __shfl_xor(v.y, o, 64);
        v.z += __shfl_xor(v.z, o, 64);
        v.w += __shfl_xor(v.w, o, 64);
    }
    return v;
}

// One 1024-thread block per head: row max + 1/sum(exp).
__global__ __launch_bounds__(1024) void stats_kernel(
        const float* __restrict__ att, float* __restrict__ stats, int M) {
    __shared__ float red[16];
    const int h = blockIdx.x;
    const float* __restrict__ row = att + (size_t)h * M;
    const int M4 = M >> 2;
    const float4* __restrict__ row4 = (const float4*)row;

    float mx = -INFINITY;
    for (int i = threadIdx.x; i < M4; i += 1024) {
        float4 v = row4[i];
        mx = fmaxf(mx, fmaxf(fmaxf(v.x, v.y), fmaxf(v.z, v.w)));
    }
    for (int i = (M4 << 2) + threadIdx.x; i < M; i += 1024) mx = fmaxf(mx, row[i]);
    mx = wred_max(mx);
    if ((threadIdx.x & 63) == 0) red[threadIdx.x >> 6] = mx;
    __syncthreads();
    float tm = red[0];
#pragma unroll
    for (int k = 1; k < 16; ++k) tm = fmaxf(tm, red[k]);
    __syncthreads();

    float s = 0.f;
    for (int i = threadIdx.x; i < M4; i += 1024) {
        float4 v = row4[i];
        s += __expf(v.x - tm) + __expf(v.y - tm) + __expf(v.z - tm) + __expf(v.w - tm);
    }
    for (int i = (M4 << 2) + threadIdx.x; i < M; i += 1024) s += __expf(row[i] - tm);
    s = wred_sum(s);
    if ((threadIdx.x & 63) == 0) red[threadIdx.x >> 6] = s;
    __syncthreads();
    if (threadIdx.x == 0) {
        float tot = 0.f;
#pragma unroll
        for (int k = 0; k < 16; ++k) tot += red[k];
        stats[h] = tm;
        stats[H + h] = 1.0f / tot;
    }
}

// Fused: blocks [0, tblocks) write transposed weight table wT[m*8+h];
// blocks [tblocks, ...) find segment ends (batch sorted -> unique writer).
__global__ __launch_bounds__(256) void prep_kernel(
        const float* __restrict__ att, const int* __restrict__ batch,
        const float* __restrict__ stats, float* __restrict__ wtabT,
        int* __restrict__ segend, int M, int Ntot, int tblocks) {
    if ((int)blockIdx.x < tblocks) {
        const int idx = blockIdx.x * 256 + threadIdx.x;
        if (idx < H * M) {
            const int hh = idx & (H - 1);
            const int mm = idx >> 3;
            wtabT[idx] = __expf(att[(size_t)hh * M + mm] - stats[hh]) * stats[H + hh];
        }
    } else {
        const int idx = (blockIdx.x - tblocks) * 256 + threadIdx.x;
        if (idx < Ntot) {
            const int b = batch[idx];
            if (idx == Ntot - 1 || batch[idx + 1] != b) segend[b] = idx + 1;
        }
    }
}

#define FMA8(XV, W0, W1)                                              \
    a0.x = fmaf(XV.x, W0.x, a0.x); a0.y = fmaf(XV.y, W0.x, a0.y);     \
    a0.z = fmaf(XV.z, W0.x, a0.z); a0.w = fmaf(XV.w, W0.x, a0.w);     \
    a1.x = fmaf(XV.x, W0.y, a1.x); a1.y = fmaf(XV.y, W0.y, a1.y);     \
    a1.z = fmaf(XV.z, W0.y, a1.z); a1.w = fmaf(XV.w, W0.y, a1.w);     \
    a2.x = fmaf(XV.x, W0.z, a2.x); a2.y = fmaf(XV.y, W0.z, a2.y);     \
    a2.z = fmaf(XV.z, W0.z, a2.z); a2.w = fmaf(XV.w, W0.z, a2.w);     \
    a3.x = fmaf(XV.x, W0.w, a3.x); a3.y = fmaf(XV.y, W0.w, a3.y);     \
    a3.z = fmaf(XV.z, W0.w, a3.z); a3.w = fmaf(XV.w, W0.w, a3.w);     \
    a4.x = fmaf(XV.x, W1.x, a4.x); a4.y = fmaf(XV.y, W1.x, a4.y);     \
    a4.z = fmaf(XV.z, W1.x, a4.z); a4.w = fmaf(XV.w, W1.x, a4.w);     \
    a5.x = fmaf(XV.x, W1.y, a5.x); a5.y = fmaf(XV.y, W1.y, a5.y);     \
    a5.z = fmaf(XV.z, W1.y, a5.z); a5.w = fmaf(XV.w, W1.y, a5.w);     \
    a6.x = fmaf(XV.x, W1.z, a6.x); a6.y = fmaf(XV.y, W1.z, a6.y);     \
    a6.z = fmaf(XV.z, W1.z, a6.z); a6.w = fmaf(XV.w, W1.z, a6.w);     \
    a7.x = fmaf(XV.x, W1.w, a7.x); a7.y = fmaf(XV.y, W1.w, a7.y);     \
    a7.z = fmaf(XV.z, W1.w, a7.z); a7.w = fmaf(XV.w, W1.w, a7.w);

#define FLUSH1(A, HH)                                                  \
    { float* o = out + (size_t)g * HC + (HH) * C + c;                  \
      atomicAdd(o + 0, A.x); atomicAdd(o + 1, A.y);                    \
      atomicAdd(o + 2, A.z); atomicAdd(o + 3, A.w); }

// Pool: wave = 64 lanes = (node_offset 0..7) x (channel_group 0..7).
// Each lane holds 8 head-accumulators (float4 each). x load per iter is one
// fully-coalesced 1KB request covering 8 nodes. Segment boundaries come from
// segend[] (batch sorted), so the inner loop is branch-free.
template <bool TABLE>
__global__ __launch_bounds__(256) void pool_kernel(
        const float* __restrict__ x, const int* __restrict__ batch,
        const float* __restrict__ att, const float* __restrict__ stats,
        const float* __restrict__ wtabT, const int* __restrict__ segend,
        float* __restrict__ out, int M, int Ntot, int chunk) {
    const int lane = threadIdx.x & 63;
    const int wid = blockIdx.x * 4 + (threadIdx.x >> 6);
    const int cg = lane & 7;
    const int no = lane >> 3;
    const int c = cg << 2;

    int n = wid * chunk;
    if (n >= Ntot) return;
    const int end = min(n + chunk, Ntot);
    int m = n % M;

    float sm_m[H], sm_i[H];
    if (!TABLE) {
#pragma unroll
        for (int hh = 0; hh < H; ++hh) { sm_m[hh] = stats[hh]; sm_i[hh] = stats[H + hh]; }
    }

    float4 a0 = {0,0,0,0}, a1 = {0,0,0,0}, a2 = {0,0,0,0}, a3 = {0,0,0,0};
    float4 a4 = {0,0,0,0}, a5 = {0,0,0,0}, a6 = {0,0,0,0}, a7 = {0,0,0,0};

    while (n < end) {
        const int g = batch[n];                 // wave-uniform, once per segment
        const int send = min(end, segend[g]);
        while (n < send) {
            const int run = min(send - n, M - m);
            const int full = run & ~7;
            const float* xb = x + (size_t)(n + no) * C + c;
            int i = 0;
#pragma unroll 2
            for (; i < full; i += 8) {
                const float4 xv = *(const float4*)(xb + (size_t)i * C);
                float4 w0, w1;
                if (TABLE) {
                    const float* wb = wtabT + ((size_t)(m + i + no) << 3);
                    w0 = *(const float4*)(wb);
                    w1 = *(const float4*)(wb + 4);
                } else {
                    const int mw = m + i + no;
                    w0.x = __expf(att[(size_t)0 * M + mw] - sm_m[0]) * sm_i[0];
                    w0.y = __expf(att[(size_t)1 * M + mw] - sm_m[1]) * sm_i[1];
                    w0.z = __expf(att[(size_t)2 * M + mw] - sm_m[2]) * sm_i[2];
                    w0.w = __expf(att[(size_t)3 * M + mw] - sm_m[3]) * sm_i[3];
                    w1.x = __expf(att[(size_t)4 * M + mw] - sm_m[4]) * sm_i[4];
                    w1.y = __expf(att[(size_t)5 * M + mw] - sm_m[5]) * sm_i[5];
                    w1.z = __expf(att[(size_t)6 * M + mw] - sm_m[6]) * sm_i[6];
                    w1.w = __expf(att[(size_t)7 * M + mw] - sm_m[7]) * sm_i[7];
                }
                FMA8(xv, w0, w1)
            }
            const int rem = run - full;
            if (rem) {
                const int nn = n + i + ((no < rem) ? no : 0);  // clamp to valid node
                const float4 xv = *(const float4*)(x + (size_t)nn * C + c);
                float4 w0 = {0,0,0,0}, w1 = {0,0,0,0};
                if (no < rem) {
                    if (TABLE) {
                        const float* wb = wtabT + ((size_t)(m + i + no) << 3);
                        w0 = *(const float4*)(wb);
                        w1 = *(const float4*)(wb + 4);
                    } else {
                        const int mw = m + i + no;
                        w0.x = __expf(att[(size_t)0 * M + mw] - sm_m[0]) * sm_i[0];
                        w0.y = __expf(att[(size_t)1 * M + mw] - sm_m[1]) * sm_i[1];
                        w0.z = __expf(att[(size_t)2 * M + mw] - sm_m[2]) * sm_i[2];
                        w0.w = __expf(att[(size_t)3 * M + mw] - sm_m[3]) * sm_i[3];
                        w1.x = __expf(att[(size_t)4 * M + mw] - sm_m[4]) * sm_i[4];
                        w1.y = __expf(att[(size_t)5 * M + mw] - sm_m[5]) * sm_i[5];
                        w1.z = __expf(att[(size_t)6 * M + mw] - sm_m[6]) * sm_i[6];
                        w1.w = __expf(att[(size_t)7 * M + mw] - sm_m[7]) * sm_i[7];
                    }
                }
                FMA8(xv, w0, w1)
            }
            n += run;
            m += run;
            if (m >= M) m = 0;
        }
        // flush segment g: reduce over node-offset axis, lanes no==0 do atomics
        a0 = red4_no(a0); a1 = red4_no(a1); a2 = red4_no(a2); a3 = red4_no(a3);
        a4 = red4_no(a4); a5 = red4_no(a5); a6 = red4_no(a6); a7 = red4_no(a7);
        if (no == 0) {
            FLUSH1(a0, 0) FLUSH1(a1, 1) FLUSH1(a2, 2) FLUSH1(a3, 3)
            FLUSH1(a4, 4) FLUSH1(a5, 5) FLUSH1(a6, 6) FLUSH1(a7, 7)
        }
        a0 = a1 = a2 = a3 = a4 = a5 = a6 = a7 = make_float4(0, 0, 0, 0);
    }
}

extern "C" void kernel_launch(void* const* d_in, const int* in_sizes, int n_in,
                              void* d_out, int out_size, void* d_ws, size_t ws_size,
                              hipStream_t stream) {
    const float* x     = (const float*)d_in[0];
    const int*   batch = (const int*)d_in[1];
    const float* att   = (const float*)d_in[2];
    float*       out   = (float*)d_out;

    const int Ntot = in_sizes[0] / C;   // total nodes
    const int M    = in_sizes[2] / H;   // nodes per graph slot axis
    const int B    = out_size / HC;     // graphs

    float* stats = (float*)d_ws;                          // 16 floats
    int*   segend = (int*)((char*)d_ws + 128);            // B ints
    const size_t wt_off = (128 + (size_t)B * 4 + 255) & ~(size_t)255;
    float* wtabT = (float*)((char*)d_ws + wt_off);        // H*M floats (transposed)
    const size_t need = wt_off + (size_t)H * M * sizeof(float);
    const bool table = (ws_size >= need);

    hipMemsetAsync(d_out, 0, (size_t)out_size * sizeof(float), stream);
    stats_kernel<<<H, 1024, 0, stream>>>(att, stats, M);

    const int tblocks = table ? (H * M + 255) / 256 : 0;
    const int sblocks = (Ntot + 255) / 256;
    prep_kernel<<<tblocks + sblocks, 256, 0, stream>>>(att, batch, stats, wtabT,
                                                       segend, M, Ntot, tblocks);

    const int chunk = 128;
    const int waves = (Ntot + chunk - 1) / chunk;
    const int blocks = (waves + 3) / 4;
    if (table) {
        pool_kernel<true><<<blocks, 256, 0, stream>>>(x, batch, att, stats, wtabT,
                                                      segend, out, M, Ntot, chunk);
    } else {
        pool_kernel<false><<<blocks, 256, 0, stream>>>(x, batch, att, stats, wtabT,
                                                       segend, out, M, Ntot, chunk);
    }
}